// Round 5
// baseline (300.951 us; speedup 1.0000x reference)
//
#include <hip/hip_runtime.h>

#define BINS 10

// R9: slash per-element issue volume. R8 evidence: duration identical whether
// inputs come from HBM (134 MB fetch) or L3 (262 KB fetch) -> NOT BW-bound;
// VALUBusy 30%, occupancy lever dead -> issue/hazard-bound in the 10-bin
// ballot loop (30 VALU + 20 SALU + 10 v_cmp->SALU hazard bubbles per elem).
// New scheme, ~11 VALU + 2 DS per element, zero SALU, zero compares:
//  - sums:  per-thread LDS column hsum[bi*256+tid], plain ds_read/add/ds_write
//           (NOT atomics — R5's failure was the atomic unit's per-lane
//           serialization; plain DS RMW is full-wave and same-wave-ordered).
//           Bank = tid%32 for any bi -> conflict-free.
//  - counts: u64 register, 10 packed 6-bit fields: pk += 1ull<<(6*bi),
//           flushed every 32 elements (max 32 per field -> no overflow).
// Accumulation order per thread is unchanged -> bit-identical result.

__device__ __forceinline__ void elem(float p, float t,
                                     float* __restrict__ col,
                                     unsigned long long* __restrict__ pk)
{
    float g  = fabsf(p - t);
    float l2 = __log2f(1.0f - g);     // bce = -ln2*log2(1-g); fold -ln2 at end
    int   bi = (int)(g * 10.0f);      // g in (0.01,0.99): bi in [0,9]
    *pk += 1ull << (6 * bi);          // packed 6-bit count, exact
    col[bi << 8] += l2;               // ds_read_b32 + v_add + ds_write_b32
}

__device__ __forceinline__ void proc4v(const float4 p, const float4 t,
                                       float* __restrict__ col,
                                       unsigned long long* __restrict__ pk)
{
    elem(p.x, t.x, col, pk); elem(p.y, t.y, col, pk);
    elem(p.z, t.z, col, pk); elem(p.w, t.w, col, pk);
}

__global__ __launch_bounds__(256, 8) void ghm_partial(
    const float4* __restrict__ p4,
    const float4* __restrict__ t4,
    float* __restrict__ gsum,          // [BINS] floats in d_ws
    unsigned int* __restrict__ gcnt,   // [BINS] uints in d_ws
    int n4)
{
    __shared__ float hsum[BINS * 256];   // 10 KB: [bin][tid] per-thread columns

    const int tid = threadIdx.x;
    for (int k = tid; k < BINS * 256; k += 256) hsum[k] = 0.0f;
    __syncthreads();

    unsigned long long pk = 0ull;        // packed per-bin counts (6 bits each)
    unsigned int cw[BINS];
#pragma unroll
    for (int b = 0; b < BINS; ++b) cw[b] = 0u;

    float* col = &hsum[tid];             // this thread's column base

    const int start  = blockIdx.x * blockDim.x + tid;
    const int stride = gridDim.x * blockDim.x;
    const int ngrp   = n4 / (4 * stride);   // 4 at 2048x256, n4 = 2^23

    // Bulk-load groups: 8 interleaved dwordx4 loads (128 B/thread in flight),
    // then a scheduling fence so the compiler cannot sink loads into compute.
    int i = start;
    for (int grp = 0; grp < ngrp; ++grp, i += 4 * stride) {
        float4 P0 = p4[i];
        float4 T0 = t4[i];
        float4 P1 = p4[i + stride];
        float4 T1 = t4[i + stride];
        float4 P2 = p4[i + 2 * stride];
        float4 T2 = t4[i + 2 * stride];
        float4 P3 = p4[i + 3 * stride];
        float4 T3 = t4[i + 3 * stride];
        __builtin_amdgcn_sched_barrier(0);  // loads above, compute below
        proc4v(P0, T0, col, &pk);
        proc4v(P1, T1, col, &pk);
        proc4v(P2, T2, col, &pk);
        proc4v(P3, T3, col, &pk);
        if (grp & 1) {                      // flush every 32 elems (<63 cap)
#pragma unroll
            for (int b = 0; b < BINS; ++b)
                cw[b] += (unsigned int)((pk >> (6 * b)) & 63ull);
            pk = 0ull;
        }
    }
    // flush main-loop leftover (odd ngrp: <=16 elems pending)
#pragma unroll
    for (int b = 0; b < BINS; ++b)
        cw[b] += (unsigned int)((pk >> (6 * b)) & 63ull);
    pk = 0ull;

    // tail: any remaining float4s (n4 not divisible by 4*stride)
    for (int j = start + ngrp * 4 * stride; j < n4; j += stride) {
        float4 p = p4[j], t = t4[j];
        proc4v(p, t, col, &pk);
#pragma unroll
        for (int b = 0; b < BINS; ++b)
            cw[b] += (unsigned int)((pk >> (6 * b)) & 63ull);
        pk = 0ull;
    }

    __syncthreads();   // all threads' hsum columns final

    // -------- epilogue: wave reduce -> LDS -> one global atomic/bin/block ----
    __shared__ float        redS[BINS];
    __shared__ unsigned int redC[BINS];
    if (tid < BINS) { redS[tid] = 0.0f; redC[tid] = 0u; }
    __syncthreads();

    const int lane = tid & 63;
#pragma unroll
    for (int b = 0; b < BINS; ++b) {
        float        s = hsum[(b << 8) + tid];   // own column value
        unsigned int c = cw[b];
#pragma unroll
        for (int off = 32; off > 0; off >>= 1) {
            s += __shfl_down(s, off);
            c += __shfl_down(c, off);
        }
        if (lane == 0) {
            atomicAdd(&redS[b], s);
            atomicAdd(&redC[b], c);
        }
    }
    __syncthreads();
    if (tid < BINS) {
        atomicAdd(&gsum[tid], redS[tid]);
        atomicAdd(&gcnt[tid], redC[tid]);
    }
}

__global__ void ghm_finalize(const float* __restrict__ gsum,
                             const unsigned int* __restrict__ gcnt,
                             float* __restrict__ out)
{
    if (threadIdx.x == 0 && blockIdx.x == 0) {
        int n = 0;
#pragma unroll
        for (int b = 0; b < BINS; ++b) n += (gcnt[b] > 0u) ? 1 : 0;
        float nn = (float)(n > 0 ? n : 1);
        float acc = 0.0f;
#pragma unroll
        for (int b = 0; b < BINS; ++b) {
            if (gcnt[b] > 0u)
                acc += gsum[b] / ((float)gcnt[b] * nn);  // counts < 2^24: exact
        }
        out[0] = -0.6931471805599453f * acc;   // fold -ln(2) from log2 domain
    }
}

extern "C" void kernel_launch(void* const* d_in, const int* in_sizes, int n_in,
                              void* d_out, int out_size, void* d_ws, size_t ws_size,
                              hipStream_t stream)
{
    const float* p = (const float*)d_in[0];   // inputs (probabilities)
    const float* t = (const float*)d_in[1];   // targets (0/1 floats)
    const int n  = in_sizes[0];               // 262144*128
    const int n4 = n >> 2;                    // divisible by 4

    float*        gsum = (float*)d_ws;
    unsigned int* gcnt = (unsigned int*)((char*)d_ws + BINS * sizeof(float));

    // d_ws is re-poisoned to 0xAA before every timed launch — zero it (capturable)
    hipMemsetAsync(d_ws, 0, BINS * (sizeof(float) + sizeof(unsigned int)), stream);

    const int threads = 256;
    const int blocks  = 2048;   // 16 float4/thread -> 4 bulk groups
    ghm_partial<<<blocks, threads, 0, stream>>>(
        (const float4*)p, (const float4*)t, gsum, gcnt, n4);

    ghm_finalize<<<1, 64, 0, stream>>>(gsum, gcnt, (float*)d_out);
}